// Round 4
// baseline (141.169 us; speedup 1.0000x reference)
//
#include <hip/hip_runtime.h>
#include <math.h>

// Problem constants (from reference setup_inputs)
#define B 64
#define S 2048
#define H 1024
#define THREADS 256
#define WAVES 4

// ---------------------------------------------------------------------------
// Pass 1: fused score + online-softmax context accumulation.
// One block = one (b, split) chunk of S/SPLIT sequence rows. Each wave owns
// whole rows (lane l holds h = c*256 + l*4 + j, c=0..3 j=0..3 -> 16 f/lane).
// 2-slot register prefetch (compile-time slot indices only — rule #20).
// VGPR budget: buf 32 + dec 16 + ctx 16 + ~20 temps ~= 84 < 102 cap of (256,5).
// ---------------------------------------------------------------------------
template <int SPLIT>
__global__ __launch_bounds__(THREADS, 5)
void luong_pass1(const float* __restrict__ dec_h,
                 const float* __restrict__ dec_c,
                 const float* __restrict__ enc,
                 float* __restrict__ attn_raw,   // d_out + B*H, raw scores
                 float* __restrict__ ctx_part,   // [B][SPLIT][H]
                 float* __restrict__ mz_part) {  // [B][SPLIT][2]
  constexpr int ROWS_PER_BLOCK = S / SPLIT;
  constexpr int RPW = ROWS_PER_BLOCK / WAVES;   // rows per wave

  const int bid  = blockIdx.x;
  const int b    = bid / SPLIT;
  const int sp   = bid % SPLIT;
  const int t    = threadIdx.x;
  const int w    = t >> 6;     // wave id 0..3
  const int lane = t & 63;

  // dec = dec_h + dec_c, distributed 16 elems per lane (same for all waves)
  float4 dec[4];
  const float4* dh = (const float4*)(dec_h + (size_t)b * H);
  const float4* dc = (const float4*)(dec_c + (size_t)b * H);
#pragma unroll
  for (int c = 0; c < 4; ++c) {
    float4 a  = dh[c * 64 + lane];
    float4 bb = dc[c * 64 + lane];
    dec[c] = make_float4(a.x + bb.x, a.y + bb.y, a.z + bb.z, a.w + bb.w);
  }

  float m = -INFINITY;
  float Z = 0.f;
  float ctx[16];
#pragma unroll
  for (int k = 0; k < 16; ++k) ctx[k] = 0.f;

  const int s_base = sp * ROWS_PER_BLOCK + w;
  // wave-local row r lives at enc[b][s_base + r*WAVES][*]
  const float4* ebase = (const float4*)(enc + ((size_t)b * S + s_base) * H);

  float4 buf[2][4];  // 2 slots x 1 row (16 floats/lane)

#define LOADR(SL, R) do {                                                      \
    const float4* rp_ = ebase + (size_t)(R) * (WAVES * (H / 4));               \
    _Pragma("unroll")                                                          \
    for (int c_ = 0; c_ < 4; ++c_) buf[SL][c_] = rp_[c_ * 64 + lane];          \
  } while (0)

#define PROCR(SL, R) do {                                                      \
    float p_ = 0.f;                                                            \
    _Pragma("unroll")                                                          \
    for (int c_ = 0; c_ < 4; ++c_)                                             \
      p_ += buf[SL][c_].x * dec[c_].x + buf[SL][c_].y * dec[c_].y +            \
            buf[SL][c_].z * dec[c_].z + buf[SL][c_].w * dec[c_].w;             \
    _Pragma("unroll")                                                          \
    for (int off_ = 32; off_ >= 1; off_ >>= 1)                                 \
      p_ += __shfl_xor(p_, off_, 64);                                          \
    if (lane == 0) attn_raw[b * S + s_base + (R) * WAVES] = p_;                \
    if (p_ > m) {                                                              \
      const float f_ = expf(m - p_);                                           \
      Z *= f_;                                                                 \
      _Pragma("unroll")                                                        \
      for (int k_ = 0; k_ < 16; ++k_) ctx[k_] *= f_;                           \
      m = p_;                                                                  \
    }                                                                          \
    const float e_ = expf(p_ - m);                                             \
    Z += e_;                                                                   \
    _Pragma("unroll")                                                          \
    for (int c_ = 0; c_ < 4; ++c_) {                                           \
      ctx[c_ * 4 + 0] += e_ * buf[SL][c_].x;                                   \
      ctx[c_ * 4 + 1] += e_ * buf[SL][c_].y;                                   \
      ctx[c_ * 4 + 2] += e_ * buf[SL][c_].z;                                   \
      ctx[c_ * 4 + 3] += e_ * buf[SL][c_].w;                                   \
    }                                                                          \
  } while (0)

  LOADR(0, 0);
#pragma unroll
  for (int i = 0; i < RPW; i += 2) {
    if (i + 1 < RPW) LOADR(1, i + 1);
    PROCR(0, i);
    if (i + 2 < RPW) LOADR(0, i + 2);
    if (i + 1 < RPW) PROCR(1, i + 1);
  }

#undef LOADR
#undef PROCR

  // ---- combine the 4 waves of this block via LDS ----
  __shared__ float ctx_lds[WAVES][H];  // 16 KiB
  __shared__ float mzs[WAVES][2];
#pragma unroll
  for (int c = 0; c < 4; ++c) {
    float4 v = make_float4(ctx[c * 4 + 0], ctx[c * 4 + 1],
                           ctx[c * 4 + 2], ctx[c * 4 + 3]);
    ((float4*)&ctx_lds[w][c * 256])[lane] = v;
  }
  if (lane == 0) { mzs[w][0] = m; mzs[w][1] = Z; }
  __syncthreads();

  const float M = fmaxf(fmaxf(mzs[0][0], mzs[1][0]),
                        fmaxf(mzs[2][0], mzs[3][0]));
  float fac[WAVES];
  float Zb = 0.f;
#pragma unroll
  for (int i = 0; i < WAVES; ++i) {
    fac[i] = expf(mzs[i][0] - M);
    Zb += mzs[i][1] * fac[i];
  }

  float* outp = ctx_part + ((size_t)b * SPLIT + sp) * H;
#pragma unroll
  for (int q = 0; q < 4; ++q) {
    const int h = q * 256 + t;
    float v = 0.f;
#pragma unroll
    for (int i = 0; i < WAVES; ++i) v += ctx_lds[i][h] * fac[i];
    outp[h] = v;
  }
  if (t == 0) {
    mz_part[(b * SPLIT + sp) * 2 + 0] = M;
    mz_part[(b * SPLIT + sp) * 2 + 1] = Zb;
  }
}

// ---------------------------------------------------------------------------
// Pass 2 (fused combine + fixup): grid = B * 4 blocks. Block (b, q4) merges
// the SPLIT partials (redundantly per block — tiny, L2-hot), writes the
// h-quarter of the context vector, and normalizes its s-quarter of attn.
// ---------------------------------------------------------------------------
template <int SPLIT>
__global__ __launch_bounds__(256)
void luong_tail(const float* __restrict__ ctx_part,
                const float* __restrict__ mz_part,
                float* __restrict__ ctx_out,   // d_out, [B][H]
                float* __restrict__ attn) {    // d_out + B*H, raw -> weights
  const int b  = blockIdx.x >> 2;
  const int q4 = blockIdx.x & 3;
  const int t  = threadIdx.x;

  const float* mz = mz_part + (size_t)b * SPLIT * 2;

  float M = -INFINITY;
#pragma unroll
  for (int i = 0; i < SPLIT; ++i) M = fmaxf(M, mz[2 * i]);
  float Z = 0.f;
#pragma unroll
  for (int i = 0; i < SPLIT; ++i) Z += mz[2 * i + 1] * expf(mz[2 * i] - M);
  const float invZ = 1.f / Z;

  __shared__ float fac_s[SPLIT];
  if (t < SPLIT) fac_s[t] = expf(mz[2 * t] - M);
  __syncthreads();

  // context quarter: h = q4*256 + t
  {
    const int h = q4 * 256 + t;
    float v = 0.f;
#pragma unroll
    for (int i = 0; i < SPLIT; ++i)
      v += ctx_part[((size_t)b * SPLIT + i) * H + h] * fac_s[i];
    ctx_out[(size_t)b * H + h] = v * invZ;
  }

  // attn quarter: s in [q4*512, q4*512 + 512)
#pragma unroll
  for (int k = 0; k < 2; ++k) {
    const int s = q4 * 512 + k * 256 + t;
    const size_t idx = (size_t)b * S + s;
    attn[idx] = expf(attn[idx] - M) * invZ;
  }
}

template <int SPLIT>
static void launch_all(const float* dec_h, const float* dec_c, const float* enc,
                       float* ctx_out, float* attn, void* d_ws,
                       hipStream_t stream) {
  float* ctx_part = (float*)d_ws;                       // B*SPLIT*H floats
  float* mz_part  = ctx_part + (size_t)B * SPLIT * H;   // B*SPLIT*2
  luong_pass1<SPLIT><<<B * SPLIT, THREADS, 0, stream>>>(dec_h, dec_c, enc,
                                                        attn, ctx_part, mz_part);
  luong_tail<SPLIT><<<B * 4, 256, 0, stream>>>(ctx_part, mz_part, ctx_out, attn);
}

extern "C" void kernel_launch(void* const* d_in, const int* in_sizes, int n_in,
                              void* d_out, int out_size, void* d_ws, size_t ws_size,
                              hipStream_t stream) {
  const float* dec_h = (const float*)d_in[0];
  const float* dec_c = (const float*)d_in[1];
  const float* enc   = (const float*)d_in[2];

  float* ctx_out = (float*)d_out;            // [B][H]
  float* attn    = (float*)d_out + B * H;    // [B][S]

  const size_t need32 = ((size_t)B * 32 * H + (size_t)B * 32 * 2) * sizeof(float);
  if (ws_size >= need32) {
    launch_all<32>(dec_h, dec_c, enc, ctx_out, attn, d_ws, stream);
  } else {
    launch_all<16>(dec_h, dec_c, enc, ctx_out, attn, d_ws, stream);
  }
}